// Round 5
// baseline (290.514 us; speedup 1.0000x reference)
//
#include <hip/hip_runtime.h>
#include <stdint.h>

#define T_DIM 2048
#define B_DIM 128
#define H_DIM 128
#define QH_DIM 1024
#define NF 32
#define KW 31
#define TB 256                 // t's per block in k2 (64 per wave, lane = t)
#define NTILE (T_DIM / TB)     // 8
#define HC 32                  // h's per staged chunk
#define TROW 33                // padded tile row (32 h + 1)

#define NEG_INF (-__builtin_inff())

typedef float v2f __attribute__((ext_vector_type(2)));

__device__ __forceinline__ float fast_tanh(float x) {
    float e = __expf(2.0f * x);
    return 1.0f - 2.0f * __builtin_amdgcn_rcpf(1.0f + e);
}

template <int C>
__device__ __forceinline__ float dpp_add(float x) {
    int m = __builtin_amdgcn_update_dpp(0, __float_as_int(x), C, 0xf, 0xf, true);
    return x + __int_as_float(m);
}
template <int C>
__device__ __forceinline__ float dpp_max(float x) {
    // bound_ctrl=false + old=src: invalid lanes take own value (identity for max)
    int m = __builtin_amdgcn_update_dpp(__float_as_int(x), __float_as_int(x), C, 0xf, 0xf, false);
    return fmaxf(x, __int_as_float(m));
}
__device__ __forceinline__ float wave_sum64(float x) {
    x = dpp_add<0x111>(x); x = dpp_add<0x112>(x); x = dpp_add<0x114>(x); x = dpp_add<0x118>(x);
    x = dpp_add<0x142>(x); x = dpp_add<0x143>(x);
    return __int_as_float(__builtin_amdgcn_readlane(__float_as_int(x), 63));
}
__device__ __forceinline__ float wave_max64(float x) {
    x = dpp_max<0x111>(x); x = dpp_max<0x112>(x); x = dpp_max<0x114>(x); x = dpp_max<0x118>(x);
    x = dpp_max<0x142>(x); x = dpp_max<0x143>(x);
    return __int_as_float(__builtin_amdgcn_readlane(__float_as_int(x), 63));
}

// k0: Gp[hp][k][p] = sum_f Wa[2hp+p, f] * conv_w[f, k]   (62 floats per h-pair row,
// laid out for uniform s_load v2f reads in k2's FIR)
__global__ void k0_G(const float* __restrict__ Wa, const float* __restrict__ conv_w,
                     float* __restrict__ Gp) {
    int gid = blockIdx.x * blockDim.x + threadIdx.x;
    if (gid >= 64 * 62) return;
    int hp = gid / 62, r = gid - hp * 62;
    int k = r >> 1, p = r & 1, h = 2 * hp + p;
    float acc = 0.0f;
    #pragma unroll
    for (int f = 0; f < NF; ++f) acc = fmaf(Wa[h * NF + f], conv_w[f * KW + k], acc);
    Gp[gid] = acc;
}

// k1: qb[b,h] = query[b,:]·Wq[h,:] + bq[h] + ba[h] + score_b[h] + Wa[h,:]·conv_b
__global__ __launch_bounds__(512)
void k1_query(const float* __restrict__ query, const float* __restrict__ Wq,
              const float* __restrict__ bq, const float* __restrict__ Wa,
              const float* __restrict__ conv_b, const float* __restrict__ ba,
              const float* __restrict__ score_b, float* __restrict__ qb) {
    const int b = blockIdx.x, tid = threadIdx.x;
    const int h = tid & 127, qtr = tid >> 7;
    __shared__ __align__(16) float qrow[QH_DIM];
    __shared__ float partial[512];
    for (int i = tid; i < QH_DIM; i += 512) qrow[i] = query[b * QH_DIM + i];
    __syncthreads();
    const float4* wq4 = (const float4*)(Wq + (size_t)h * QH_DIM + qtr * 256);
    const float4* q4 = (const float4*)(qrow + qtr * 256);
    float acc = 0.0f;
    #pragma unroll 4
    for (int j = 0; j < 64; ++j) {
        float4 w = wq4[j], q = q4[j];
        acc += w.x * q.x + w.y * q.y + w.z * q.z + w.w * q.w;
    }
    if (qtr == 0) {
        float cb = bq[h] + ba[h] + score_b[h];
        #pragma unroll
        for (int f = 0; f < NF; ++f) cb = fmaf(Wa[h * NF + f], conv_b[f], cb);
        acc += cb;
    }
    partial[tid] = acc;
    __syncthreads();
    if (tid < 128) qb[b * H_DIM + h] = partial[h] + partial[h + 128] + partial[h + 256] + partial[h + 384];
}

// k2: fused score + online softmax + context partials. lane = t (tid = local t).
// Phase A: FIR taps per-lane in VGPRs, G rows uniform (s_load), enc via LDS tile
// (h-chunked, prefetch double-buffered in registers). Score accumulates per lane
// over the h loop — no cross-lane ops in the hot loop.
// Phase B: e_t from LDS broadcast; context fold re-reads enc coalesced (L2/L3-hot).
__global__ __launch_bounds__(256, 4)
void k2_fused(const float* __restrict__ enc, const float* __restrict__ cum,
              const void* __restrict__ mask, const float* __restrict__ Gp,
              const float* __restrict__ qb, const float* __restrict__ score_w,
              float* __restrict__ s_out, float* __restrict__ o_part,
              float* __restrict__ ml_part) {
    const int b = blockIdx.x;          // b fastest: co-resident blocks cover a t-slab
    const int tl = blockIdx.y;
    const int t0 = tl * TB;
    const int tid = threadIdx.x;
    const int l = tid & 63, wv = tid >> 6;

    __shared__ float tile[TB][TROW];   // 33.8 KB
    __shared__ float cw[TB + 30];
    __shared__ float esh[TB];
    __shared__ float oc[4][H_DIM];
    __shared__ float mwl[4], lwl[4];

    // mask layout probe + this thread's mask -> score init (0 or -inf)
    float s;
    {
        uint32_t u = ((const uint32_t*)mask)[l];
        unsigned long long hi = __ballot(u > 1u);
        unsigned long long nf = __ballot(u != 0u && u != 0x3f800000u);
        int layout = (hi == 0ull) ? 0 : ((nf == 0ull) ? 2 : 1);
        const int idx = b * T_DIM + t0 + tid;
        bool m;
        if (layout == 0)      m = ((const int32_t*)mask)[idx] != 0;
        else if (layout == 1) m = ((const uint8_t*)mask)[idx] != 0;
        else                  m = ((const float*)mask)[idx] != 0.0f;
        s = m ? NEG_INF : 0.0f;
    }

    // stage cum window [t0-15, t0+TB+15)
    {
        int tg = t0 - 15 + tid;
        cw[tid] = (tg >= 0 && tg < T_DIM) ? cum[b * T_DIM + tg] : 0.0f;
        if (tid < TB + 30 - 256) {
            int j = 256 + tid;
            int tg2 = t0 - 15 + j;
            cw[j] = (tg2 >= 0 && tg2 < T_DIM) ? cum[b * T_DIM + tg2] : 0.0f;
        }
    }

    // prefetch enc chunk 0 into registers (coalesced float4)
    const float* encb = enc + (size_t)t0 * (B_DIM * H_DIM) + b * H_DIM;
    float4 pf[8];
    #pragma unroll
    for (int p = 0; p < 8; ++p) {
        int g = p * 256 + tid;
        int t = g >> 3, hq = g & 7;
        pf[p] = *(const float4*)(encb + (size_t)t * (B_DIM * H_DIM) + 4 * hq);
    }

    __syncthreads();   // cw ready

    float tp[KW];      // per-lane 31-tap window (lane-distinct, legitimately VGPR)
    #pragma unroll
    for (int k = 0; k < KW; ++k) tp[k] = cw[tid + k];

    #pragma unroll
    for (int j = 0; j < 4; ++j) {
        // commit prefetched chunk j to LDS
        #pragma unroll
        for (int p = 0; p < 8; ++p) {
            int g = p * 256 + tid;
            int t = g >> 3, hq = g & 7;
            *(float4*)&tile[t][4 * hq] = pf[p];
        }
        __syncthreads();
        // prefetch chunk j+1 (overlaps with compute below)
        if (j < 3) {
            #pragma unroll
            for (int p = 0; p < 8; ++p) {
                int g = p * 256 + tid;
                int t = g >> 3, hq = g & 7;
                pf[p] = *(const float4*)(encb + (size_t)t * (B_DIM * H_DIM) + (j + 1) * HC + 4 * hq);
            }
        }
        // compute 16 h-pairs of this chunk; G/qb/score_w reads are loop-uniform -> s_load
        #pragma unroll
        for (int hp = 0; hp < 16; ++hp) {
            const int hg = j * HC + 2 * hp;
            const float* gr = Gp + (j * 16 + hp) * 62;
            v2f accA = { qb[b * H_DIM + hg], qb[b * H_DIM + hg + 1] };
            v2f accB = { 0.0f, 0.0f };
            #pragma unroll
            for (int k = 0; k < 16; ++k) {
                const v2f g2 = *(const v2f*)(gr + 2 * k);
                accA = __builtin_elementwise_fma(g2, (v2f){tp[k], tp[k]}, accA);
            }
            #pragma unroll
            for (int k = 16; k < KW; ++k) {
                const v2f g2 = *(const v2f*)(gr + 2 * k);
                accB = __builtin_elementwise_fma(g2, (v2f){tp[k], tp[k]}, accB);
            }
            const v2f e2 = *(const v2f*)&tile[tid][2 * hp];   // lane-stride 33: conflict-free
            const v2f a2 = accA + accB + e2;
            s += score_w[hg] * fast_tanh(a2.x) + score_w[hg + 1] * fast_tanh(a2.y);
        }
        __syncthreads();
    }

    // raw masked score out (coalesced, lane = t)
    s_out[b * T_DIM + t0 + tid] = s;

    // wave softmax stats (single DPP reduction pair per wave)
    const float m_w = wave_max64(s);
    const float m_use = (m_w == NEG_INF) ? 0.0f : m_w;
    const float e = __expf(s - m_use);
    const float l_w = wave_sum64(e);
    esh[tid] = e;
    __syncthreads();

    // context fold: lane owns h-pair {2l,2l+1}; wave folds its own 64 t's.
    // enc re-read is coalesced 512B rows, L2/L3-hot from phase A.
    const float* ep = enc + ((size_t)(t0 + wv * 64) * B_DIM + b) * H_DIM + 2 * l;
    v2f oa = {0.0f, 0.0f}, ob = {0.0f, 0.0f};
    #pragma unroll 8
    for (int i = 0; i < 64; i += 2) {
        const float e0 = esh[wv * 64 + i];
        const float e1 = esh[wv * 64 + i + 1];
        const v2f v0 = *(const v2f*)(ep + (size_t)i * (B_DIM * H_DIM));
        const v2f v1 = *(const v2f*)(ep + (size_t)(i + 1) * (B_DIM * H_DIM));
        oa = __builtin_elementwise_fma((v2f){e0, e0}, v0, oa);
        ob = __builtin_elementwise_fma((v2f){e1, e1}, v1, ob);
    }
    const v2f o2 = oa + ob;
    oc[wv][2 * l] = o2.x;
    oc[wv][2 * l + 1] = o2.y;
    if (l == 0) { mwl[wv] = m_w; lwl[wv] = l_w; }
    __syncthreads();
    if (tid < H_DIM) {
        const float mb = fmaxf(fmaxf(mwl[0], mwl[1]), fmaxf(mwl[2], mwl[3]));
        const float mu = (mb == NEG_INF) ? 0.0f : mb;
        const float b0 = __expf(mwl[0] - mu), b1 = __expf(mwl[1] - mu);
        const float b2 = __expf(mwl[2] - mu), b3 = __expf(mwl[3] - mu);
        const float o = oc[0][tid] * b0 + oc[1][tid] * b1 + oc[2][tid] * b2 + oc[3][tid] * b3;
        const int tb = b * NTILE + tl;
        o_part[tb * H_DIM + tid] = o;
        if (tid == 0) {
            ml_part[tb * 2] = mb;
            ml_part[tb * 2 + 1] = lwl[0] * b0 + lwl[1] * b1 + lwl[2] * b2 + lwl[3] * b3;
        }
    }
}

// k5: per-b global combine + alignment/cum epilogue
__global__ __launch_bounds__(256)
void k5_final(float* __restrict__ s_align, const float* __restrict__ cum_in,
              float* __restrict__ cum_out, const float* __restrict__ o_part,
              const float* __restrict__ ml_part, float* __restrict__ ctx) {
    const int b = blockIdx.x, tid = threadIdx.x;
    __shared__ float sm[NTILE], sl[NTILE], sb[NTILE];
    if (tid < NTILE) {
        sm[tid] = ml_part[(b * NTILE + tid) * 2];
        sl[tid] = ml_part[(b * NTILE + tid) * 2 + 1];
    }
    __syncthreads();
    float M = sm[0];
    #pragma unroll
    for (int i = 1; i < NTILE; ++i) M = fmaxf(M, sm[i]);
    const float M_use = (M == NEG_INF) ? 0.0f : M;
    if (tid < NTILE) sb[tid] = __expf(sm[tid] - M_use);
    __syncthreads();
    float L = 0.0f;
    #pragma unroll
    for (int i = 0; i < NTILE; ++i) L = fmaf(sl[i], sb[i], L);
    const float invL = 1.0f / L;
    if (tid < H_DIM) {
        float o = 0.0f;
        #pragma unroll
        for (int i = 0; i < NTILE; ++i)
            o = fmaf(o_part[(b * NTILE + i) * H_DIM + tid], sb[i], o);
        ctx[b * H_DIM + tid] = o * invL;
    }
    #pragma unroll
    for (int j = 0; j < 8; ++j) {
        const int idx = b * T_DIM + tid + j * 256;
        const float a = __expf(s_align[idx] - M_use) * invL;
        s_align[idx] = a;
        cum_out[idx] = cum_in[idx] + a;
    }
}

extern "C" void kernel_launch(void* const* d_in, const int* in_sizes, int n_in,
                              void* d_out, int out_size, void* d_ws, size_t ws_size,
                              hipStream_t stream) {
    const float* enc     = (const float*)d_in[0];
    const void*  mask    = d_in[1];
    const float* query   = (const float*)d_in[2];
    const float* cum     = (const float*)d_in[3];
    const float* conv_w  = (const float*)d_in[4];
    const float* conv_b  = (const float*)d_in[5];
    const float* Wq      = (const float*)d_in[6];
    const float* bq      = (const float*)d_in[7];
    const float* Wa      = (const float*)d_in[8];
    const float* ba      = (const float*)d_in[9];
    const float* score_w = (const float*)d_in[10];
    const float* score_b = (const float*)d_in[11];

    float* ctx_out   = (float*)d_out;                    // [B,H]
    float* cum_out   = ctx_out + B_DIM * H_DIM;          // [B,T]
    float* align_out = cum_out + B_DIM * T_DIM;          // [B,T]

    float* Gp     = (float*)d_ws;                        // [64 hp][62]  (pad 4096)
    float* qb     = Gp + 4096;                           // [B,H]
    float* o_part = qb + B_DIM * H_DIM;                  // [B,NTILE,H]
    float* ml     = o_part + B_DIM * NTILE * H_DIM;      // [B,NTILE,2]

    k0_G<<<16, 256, 0, stream>>>(Wa, conv_w, Gp);
    k1_query<<<B_DIM, 512, 0, stream>>>(query, Wq, bq, Wa, conv_b, ba, score_b, qb);
    k2_fused<<<dim3(B_DIM, NTILE), 256, 0, stream>>>(enc, cum, mask, Gp, qb, score_w,
                                                     align_out, o_part, ml);
    k5_final<<<B_DIM, 256, 0, stream>>>(align_out, cum, cum_out, o_part, ml, ctx_out);
}

// Round 6
// 285.408 us; speedup vs baseline: 1.0179x; 1.0179x over previous
//
#include <hip/hip_runtime.h>
#include <stdint.h>

#define T_DIM 2048
#define B_DIM 128
#define H_DIM 128
#define QH_DIM 1024
#define NF 32
#define KW 31
#define TB 128                 // t's per block in k2; full tile persists in LDS
#define NTILE (T_DIM / TB)     // 16
#define SROW 132               // LDS tile row stride in floats (16B-aligned pad)

#define NEG_INF (-__builtin_inff())

typedef float v2f __attribute__((ext_vector_type(2)));

__device__ __forceinline__ float fast_tanh(float x) {
    float e = __expf(2.0f * x);
    return 1.0f - 2.0f * __builtin_amdgcn_rcpf(1.0f + e);
}

template <int C>
__device__ __forceinline__ float dpp_add(float x) {
    int m = __builtin_amdgcn_update_dpp(0, __float_as_int(x), C, 0xf, 0xf, true);
    return x + __int_as_float(m);
}
template <int C>
__device__ __forceinline__ float dpp_max(float x) {
    int m = __builtin_amdgcn_update_dpp(__float_as_int(x), __float_as_int(x), C, 0xf, 0xf, false);
    return fmaxf(x, __int_as_float(m));
}
__device__ __forceinline__ float wave_sum64(float x) {
    x = dpp_add<0x111>(x); x = dpp_add<0x112>(x); x = dpp_add<0x114>(x); x = dpp_add<0x118>(x);
    x = dpp_add<0x142>(x); x = dpp_add<0x143>(x);
    return __int_as_float(__builtin_amdgcn_readlane(__float_as_int(x), 63));
}
__device__ __forceinline__ float wave_max64(float x) {
    x = dpp_max<0x111>(x); x = dpp_max<0x112>(x); x = dpp_max<0x114>(x); x = dpp_max<0x118>(x);
    x = dpp_max<0x142>(x); x = dpp_max<0x143>(x);
    return __int_as_float(__builtin_amdgcn_readlane(__float_as_int(x), 63));
}

// k0: Gp[hp][k][p] = sum_f Wa[2hp+p, f] * conv_w[f, k]  (62 floats per h-pair row,
// consumed in k2 via uniform s_load)
__global__ void k0_G(const float* __restrict__ Wa, const float* __restrict__ conv_w,
                     float* __restrict__ Gp) {
    int gid = blockIdx.x * blockDim.x + threadIdx.x;
    if (gid >= 64 * 62) return;
    int hp = gid / 62, r = gid - hp * 62;
    int k = r >> 1, p = r & 1, h = 2 * hp + p;
    float acc = 0.0f;
    #pragma unroll
    for (int f = 0; f < NF; ++f) acc = fmaf(Wa[h * NF + f], conv_w[f * KW + k], acc);
    Gp[gid] = acc;
}

// k1: qb[b,h] = query[b,:]·Wq[h,:] + bq[h] + ba[h] + score_b[h] + Wa[h,:]·conv_b
__global__ __launch_bounds__(512)
void k1_query(const float* __restrict__ query, const float* __restrict__ Wq,
              const float* __restrict__ bq, const float* __restrict__ Wa,
              const float* __restrict__ conv_b, const float* __restrict__ ba,
              const float* __restrict__ score_b, float* __restrict__ qb) {
    const int b = blockIdx.x, tid = threadIdx.x;
    const int h = tid & 127, qtr = tid >> 7;
    __shared__ __align__(16) float qrow[QH_DIM];
    __shared__ float partial[512];
    for (int i = tid; i < QH_DIM; i += 512) qrow[i] = query[b * QH_DIM + i];
    __syncthreads();
    const float4* wq4 = (const float4*)(Wq + (size_t)h * QH_DIM + qtr * 256);
    const float4* q4 = (const float4*)(qrow + qtr * 256);
    float acc = 0.0f;
    #pragma unroll 4
    for (int j = 0; j < 64; ++j) {
        float4 w = wq4[j], q = q4[j];
        acc += w.x * q.x + w.y * q.y + w.z * q.z + w.w * q.w;
    }
    if (qtr == 0) {
        float cb = bq[h] + ba[h] + score_b[h];
        #pragma unroll
        for (int f = 0; f < NF; ++f) cb = fmaf(Wa[h * NF + f], conv_b[f], cb);
        acc += cb;
    }
    partial[tid] = acc;
    __syncthreads();
    if (tid < 128) qb[b * H_DIM + h] = partial[h] + partial[h + 128] + partial[h + 256] + partial[h + 384];
}

// k2: fused score + online softmax + context partials, enc read from HBM once.
// Wave wv -> (tg = wv&1 : t-group of 64, hh = wv>>1 : h-half of 64).
// Phase A (lane = t): FIR taps per-lane VGPRs; G/qb/score_w via uniform s_load
// (hh readfirstlane'd); enc from persistent LDS tile. Per-wave partial score
// over its h-half -> LDS combine (no per-t cross-lane reduction at all).
// Phase B (lane = h-pair): context fold straight from the LDS tile.
__global__ __launch_bounds__(256, 2)
void k2_fused(const float* __restrict__ enc, const float* __restrict__ cum,
              const void* __restrict__ mask, const float* __restrict__ Gp,
              const float* __restrict__ qb, const float* __restrict__ score_w,
              float* __restrict__ s_out, float* __restrict__ o_part,
              float* __restrict__ ml_part) {
    const int b = blockIdx.x;      // b fastest: co-dispatched blocks read adjacent 512B
    const int tl = blockIdx.y;
    const int t0 = tl * TB;
    const int tid = threadIdx.x;
    const int l = tid & 63;
    const int wv = __builtin_amdgcn_readfirstlane(tid >> 6);   // uniform for s_load
    const int tg = wv & 1, hh = wv >> 1;

    __shared__ float tile[TB * SROW];   // 67584 B, persists across both phases
    __shared__ float cw[TB + 30];
    __shared__ float sp[2][TB];
    __shared__ float esh[TB];
    __shared__ float oc[4][H_DIM];
    __shared__ float mwl[2], lwl[2];

    // stage enc tile (coalesced float4; load->store pairs, low reg pressure)
    const float* encb = enc + (size_t)t0 * (B_DIM * H_DIM) + (size_t)b * H_DIM;
    #pragma unroll
    for (int i = 0; i < 16; ++i) {
        const int n = i * 256 + tid;
        const int t = n >> 5, q = n & 31;
        const float4 v = *(const float4*)(encb + (size_t)t * (B_DIM * H_DIM) + 4 * q);
        *(float4*)&tile[t * SROW + 4 * q] = v;
    }
    if (tid < TB + 30) {
        const int tg_ = t0 - 15 + tid;
        cw[tid] = (tg_ >= 0 && tg_ < T_DIM) ? cum[b * T_DIM + tg_] : 0.0f;
    }
    __syncthreads();

    // per-lane 31-tap window (lane-distinct -> legitimately VGPR)
    float tp[KW];
    #pragma unroll
    for (int k = 0; k < KW; ++k) tp[k] = cw[tg * 64 + l + k];

    const int trow = (tg * 64 + l) * SROW;
    float s_half = 0.0f;

    #pragma unroll
    for (int c = 0; c < 2; ++c) {
        v2f acc[16];
        #pragma unroll
        for (int hp = 0; hp < 16; ++hp) {
            const int h0 = hh * 64 + c * 32 + 2 * hp;
            acc[hp] = *(const v2f*)(qb + b * H_DIM + h0);       // uniform -> s_load
        }
        #pragma unroll
        for (int hp = 0; hp < 16; ++hp) {
            const float* gr = Gp + (hh * 32 + c * 16 + hp) * 62; // uniform rows
            v2f a = acc[hp];
            #pragma unroll
            for (int k = 0; k < KW; ++k) {
                const v2f g2 = *(const v2f*)(gr + 2 * k);        // s_load
                a = __builtin_elementwise_fma(g2, (v2f){tp[k], tp[k]}, a);
            }
            acc[hp] = a;
        }
        #pragma unroll
        for (int hp = 0; hp < 16; ++hp) {
            const int h0 = hh * 64 + c * 32 + 2 * hp;
            const v2f e2 = *(const v2f*)&tile[trow + h0];
            const v2f a2 = acc[hp] + e2;
            s_half += score_w[h0] * fast_tanh(a2.x) + score_w[h0 + 1] * fast_tanh(a2.y);
        }
    }
    sp[hh][tg * 64 + l] = s_half;
    __syncthreads();

    if (hh == 0) {
        // combine halves, mask, wave softmax stats (lane = t, 64 distinct t's)
        uint32_t u = ((const uint32_t*)mask)[l];
        unsigned long long hi = __ballot(u > 1u);
        unsigned long long nf = __ballot(u != 0u && u != 0x3f800000u);
        const int layout = (hi == 0ull) ? 0 : ((nf == 0ull) ? 2 : 1);
        const int t = tg * 64 + l;
        const int gidx = b * T_DIM + t0 + t;
        bool msk;
        if (layout == 0)      msk = ((const int32_t*)mask)[gidx] != 0;
        else if (layout == 1) msk = ((const uint8_t*)mask)[gidx] != 0;
        else                  msk = ((const float*)mask)[gidx] != 0.0f;
        float s = sp[0][t] + sp[1][t];
        s = msk ? NEG_INF : s;
        s_out[gidx] = s;
        const float m_w = wave_max64(s);
        const float m_use = (m_w == NEG_INF) ? 0.0f : m_w;
        const float e = __expf(s - m_use);
        const float l_w = wave_sum64(e);
        esh[t] = e;
        if (l == 0) { mwl[tg] = m_w; lwl[tg] = l_w; }
    }
    __syncthreads();

    // context fold from LDS tile: wave wv folds t in [wv*32, wv*32+32), lane = h-pair
    {
        const int tb_ = wv * 32;
        v2f o2 = {0.0f, 0.0f};
        #pragma unroll 8
        for (int i = 0; i < 32; ++i) {
            const float e = esh[tb_ + i];
            const v2f v = *(const v2f*)&tile[(tb_ + i) * SROW + 2 * l];
            o2 = __builtin_elementwise_fma((v2f){e, e}, v, o2);
        }
        oc[wv][2 * l] = o2.x;
        oc[wv][2 * l + 1] = o2.y;
    }
    __syncthreads();

    if (tid < H_DIM) {
        const float m0 = mwl[0], m1 = mwl[1];
        const float mb = fmaxf(m0, m1);
        const float mu = (mb == NEG_INF) ? 0.0f : mb;
        const float b0 = __expf(m0 - mu), b1 = __expf(m1 - mu);
        const float o = (oc[0][tid] + oc[1][tid]) * b0 + (oc[2][tid] + oc[3][tid]) * b1;
        const int tbase = b * NTILE + tl;
        o_part[tbase * H_DIM + tid] = o;
        if (tid == 0) {
            ml_part[tbase * 2] = mb;
            ml_part[tbase * 2 + 1] = lwl[0] * b0 + lwl[1] * b1;
        }
    }
}

// k5: per-b global combine + alignment/cum epilogue
__global__ __launch_bounds__(256)
void k5_final(float* __restrict__ s_align, const float* __restrict__ cum_in,
              float* __restrict__ cum_out, const float* __restrict__ o_part,
              const float* __restrict__ ml_part, float* __restrict__ ctx) {
    const int b = blockIdx.x, tid = threadIdx.x;
    __shared__ float sm[NTILE], sl[NTILE], sb[NTILE];
    if (tid < NTILE) {
        sm[tid] = ml_part[(b * NTILE + tid) * 2];
        sl[tid] = ml_part[(b * NTILE + tid) * 2 + 1];
    }
    __syncthreads();
    float M = sm[0];
    #pragma unroll
    for (int i = 1; i < NTILE; ++i) M = fmaxf(M, sm[i]);
    const float M_use = (M == NEG_INF) ? 0.0f : M;
    if (tid < NTILE) sb[tid] = __expf(sm[tid] - M_use);
    __syncthreads();
    float L = 0.0f;
    #pragma unroll
    for (int i = 0; i < NTILE; ++i) L = fmaf(sl[i], sb[i], L);
    const float invL = 1.0f / L;
    if (tid < H_DIM) {
        float o = 0.0f;
        #pragma unroll
        for (int i = 0; i < NTILE; ++i)
            o = fmaf(o_part[(b * NTILE + i) * H_DIM + tid], sb[i], o);
        ctx[b * H_DIM + tid] = o * invL;
    }
    #pragma unroll
    for (int j = 0; j < 8; ++j) {
        const int idx = b * T_DIM + tid + j * 256;
        const float a = __expf(s_align[idx] - M_use) * invL;
        s_align[idx] = a;
        cum_out[idx] = cum_in[idx] + a;
    }
}

extern "C" void kernel_launch(void* const* d_in, const int* in_sizes, int n_in,
                              void* d_out, int out_size, void* d_ws, size_t ws_size,
                              hipStream_t stream) {
    const float* enc     = (const float*)d_in[0];
    const void*  mask    = d_in[1];
    const float* query   = (const float*)d_in[2];
    const float* cum     = (const float*)d_in[3];
    const float* conv_w  = (const float*)d_in[4];
    const float* conv_b  = (const float*)d_in[5];
    const float* Wq      = (const float*)d_in[6];
    const float* bq      = (const float*)d_in[7];
    const float* Wa      = (const float*)d_in[8];
    const float* ba      = (const float*)d_in[9];
    const float* score_w = (const float*)d_in[10];
    const float* score_b = (const float*)d_in[11];

    float* ctx_out   = (float*)d_out;                    // [B,H]
    float* cum_out   = ctx_out + B_DIM * H_DIM;          // [B,T]
    float* align_out = cum_out + B_DIM * T_DIM;          // [B,T]

    float* Gp     = (float*)d_ws;                        // [64 hp][62] (pad 4096)
    float* qb     = Gp + 4096;                           // [B,H]
    float* o_part = qb + B_DIM * H_DIM;                  // [B,NTILE,H]
    float* ml     = o_part + B_DIM * NTILE * H_DIM;      // [B,NTILE,2]

    k0_G<<<16, 256, 0, stream>>>(Wa, conv_w, Gp);
    k1_query<<<B_DIM, 512, 0, stream>>>(query, Wq, bq, Wa, conv_b, ba, score_b, qb);
    k2_fused<<<dim3(B_DIM, NTILE), 256, 0, stream>>>(enc, cum, mask, Gp, qb, score_w,
                                                     align_out, o_part, ml);
    k5_final<<<B_DIM, 256, 0, stream>>>(align_out, cum, cum_out, o_part, ml, ctx_out);
}

// Round 7
// 244.648 us; speedup vs baseline: 1.1875x; 1.1666x over previous
//
#include <hip/hip_runtime.h>
#include <stdint.h>

#define T_DIM 2048
#define B_DIM 128
#define H_DIM 128
#define QH_DIM 1024
#define NF 32
#define KW 31
#define TB 128                 // t's per block (4 waves x 32 t)
#define NTILE (T_DIM / TB)     // 16
#define CPAD_ROW (T_DIM + 32)

#define NEG_INF (-__builtin_inff())

typedef float v2f __attribute__((ext_vector_type(2)));

__device__ __forceinline__ float fast_tanh(float x) {
    float e = __expf(2.0f * x);
    return 1.0f - 2.0f * __builtin_amdgcn_rcpf(1.0f + e);
}

template <int C>
__device__ __forceinline__ float dpp_add(float x) {
    int m = __builtin_amdgcn_update_dpp(0, __float_as_int(x), C, 0xf, 0xf, true);
    return x + __int_as_float(m);
}
// full 64-lane sum; result lands wave-uniform (readlane -> SGPR)
__device__ __forceinline__ float wave_sum64(float x) {
    x = dpp_add<0x111>(x); x = dpp_add<0x112>(x); x = dpp_add<0x114>(x); x = dpp_add<0x118>(x);
    x = dpp_add<0x142>(x); x = dpp_add<0x143>(x);
    return __int_as_float(__builtin_amdgcn_readlane(__float_as_int(x), 63));
}

// k_prep: cpad[b][j] = cum[b][j-16] with 16-zero pads (taps: cum[t-15+k] = cpad[t+1+k]);
// mbias[b][t] = 0 / -inf. Both consumed as uniform s_loads in k2.
__global__ __launch_bounds__(256)
void k_prep(const float* __restrict__ cum, const void* __restrict__ mask,
            float* __restrict__ cpad, float* __restrict__ mbias) {
    const int gid = blockIdx.x * 256 + threadIdx.x;   // B*T
    const int b = gid >> 11, t = gid & 2047;
    const int l = threadIdx.x & 63;
    uint32_t u = ((const uint32_t*)mask)[l];
    unsigned long long hi = __ballot(u > 1u);
    unsigned long long nf = __ballot(u != 0u && u != 0x3f800000u);
    int layout = (hi == 0ull) ? 0 : ((nf == 0ull) ? 2 : 1);  // int32 / byte / float
    bool m;
    if (layout == 0)      m = ((const int32_t*)mask)[gid] != 0;
    else if (layout == 1) m = ((const uint8_t*)mask)[gid] != 0;
    else                  m = ((const float*)mask)[gid] != 0.0f;
    mbias[gid] = m ? NEG_INF : 0.0f;
    cpad[b * CPAD_ROW + 16 + t] = cum[gid];
    if (t < 16) cpad[b * CPAD_ROW + t] = 0.0f;
    else if (t >= T_DIM - 16) cpad[b * CPAD_ROW + 32 + t] = 0.0f;
}

// k0: Gt[k][h] = sum_f Wa[h,f] * conv_w[f,k]  ([k][h] layout: k2 lane loads b64 per k)
__global__ void k0_G(const float* __restrict__ Wa, const float* __restrict__ conv_w,
                     float* __restrict__ Gt) {
    int gid = blockIdx.x * blockDim.x + threadIdx.x;
    if (gid >= KW * H_DIM) return;
    int k = gid >> 7, h = gid & 127;
    float acc = 0.0f;
    #pragma unroll
    for (int f = 0; f < NF; ++f) acc = fmaf(Wa[h * NF + f], conv_w[f * KW + k], acc);
    Gt[gid] = acc;
}

// k1: qb[b,h] = query[b,:]·Wq[h,:] + bq[h] + ba[h] + score_b[h] + Wa[h,:]·conv_b
__global__ __launch_bounds__(512)
void k1_query(const float* __restrict__ query, const float* __restrict__ Wq,
              const float* __restrict__ bq, const float* __restrict__ Wa,
              const float* __restrict__ conv_b, const float* __restrict__ ba,
              const float* __restrict__ score_b, float* __restrict__ qb) {
    const int b = blockIdx.x, tid = threadIdx.x;
    const int h = tid & 127, qtr = tid >> 7;
    __shared__ __align__(16) float qrow[QH_DIM];
    __shared__ float partial[512];
    for (int i = tid; i < QH_DIM; i += 512) qrow[i] = query[b * QH_DIM + i];
    __syncthreads();
    const float4* wq4 = (const float4*)(Wq + (size_t)h * QH_DIM + qtr * 256);
    const float4* q4 = (const float4*)(qrow + qtr * 256);
    float acc = 0.0f;
    #pragma unroll 4
    for (int j = 0; j < 64; ++j) {
        float4 w = wq4[j], q = q4[j];
        acc += w.x * q.x + w.y * q.y + w.z * q.z + w.w * q.w;
    }
    if (qtr == 0) {
        float cb = bq[h] + ba[h] + score_b[h];
        #pragma unroll
        for (int f = 0; f < NF; ++f) cb = fmaf(Wa[h * NF + f], conv_b[f], cb);
        acc += cb;
    }
    partial[tid] = acc;
    __syncthreads();
    if (tid < 128) qb[b * H_DIM + h] = partial[h] + partial[h + 128] + partial[h + 256] + partial[h + 384];
}

// k2: fused score + online softmax + context partials, single enc read.
// Wave = 32 t's of one b; lane = h-pair {2l, 2l+1}.
// G: 31 v2f in VGPRs (loaded once). Taps + mask bias: uniform s_loads (SGPRs).
// enc row: one coalesced b64 per t, consumed by score AND context fold while
// live in registers. Score reduce: DPP (VALU-only), result -> SGPR.
__global__ __launch_bounds__(256, 2)
void k2_fused(const float* __restrict__ enc, const float* __restrict__ cpad,
              const float* __restrict__ mbias, const float* __restrict__ Gt,
              const float* __restrict__ qb, const float* __restrict__ score_w,
              float* __restrict__ s_out, float* __restrict__ o_part,
              float* __restrict__ ml_part) {
    const int b = blockIdx.x;      // b fastest: co-dispatched blocks read adjacent 512B
    const int tl = blockIdx.y;
    const int tid = threadIdx.x;
    const int l = tid & 63;
    const int wv = __builtin_amdgcn_readfirstlane(tid >> 6);
    const int tw0 = tl * TB + wv * 32;

    __shared__ float oc[4][H_DIM];
    __shared__ float mwl[4], lwl[4];

    v2f G[KW];                     // 62 VGPRs, lane-distinct, loaded once
    #pragma unroll
    for (int k = 0; k < KW; ++k) G[k] = *(const v2f*)(Gt + k * H_DIM + 2 * l);

    const v2f base = *(const v2f*)(qb + b * H_DIM + 2 * l);
    const v2f w2 = *(const v2f*)(score_w + 2 * l);
    const float* crow = cpad + b * CPAD_ROW;
    const float* mrow = mbias + b * T_DIM;

    float m_w = NEG_INF, l_w = 0.0f;
    v2f o = {0.0f, 0.0f};
    float sv = 0.0f;

    #pragma unroll
    for (int c = 0; c < 4; ++c) {
        const int tb = tw0 + c * 8;

        float sc[38];              // uniform -> SGPRs
        #pragma unroll
        for (int j = 0; j < 38; ++j) sc[j] = crow[tb + 1 + j];

        v2f ee[8];
        #pragma unroll
        for (int it = 0; it < 8; ++it)
            ee[it] = *(const v2f*)(enc + ((size_t)(tb + it) * B_DIM + b) * H_DIM + 2 * l);

        float su[8];
        #pragma unroll
        for (int it = 0; it < 8; ++it) {
            v2f acc = base;
            #pragma unroll
            for (int k = 0; k < KW; ++k)
                acc = __builtin_elementwise_fma(G[k], (v2f){sc[it + k], sc[it + k]}, acc);
            const v2f a2 = acc + ee[it];
            float p = w2.x * fast_tanh(a2.x) + w2.y * fast_tanh(a2.y);
            su[it] = wave_sum64(p) + mrow[tb + it];
        }

        // stash this chunk's (wave-uniform) scores into per-lane slots for output
        #pragma unroll
        for (int it = 0; it < 8; ++it) sv = (l == c * 8 + it) ? su[it] : sv;

        // online-softmax fold (enc rows still in registers)
        float m8 = su[0];
        #pragma unroll
        for (int it = 1; it < 8; ++it) m8 = fmaxf(m8, su[it]);
        const float m_new = fmaxf(m_w, m8);
        const float m_use = (m_new == NEG_INF) ? 0.0f : m_new;
        const float alpha = __expf(m_w - m_use);
        float lsum = 0.0f;
        v2f osum = {0.0f, 0.0f};
        #pragma unroll
        for (int it = 0; it < 8; ++it) {
            const float e = __expf(su[it] - m_use);
            lsum += e;
            osum = __builtin_elementwise_fma((v2f){e, e}, ee[it], osum);
        }
        l_w = fmaf(l_w, alpha, lsum);
        o = __builtin_elementwise_fma(o, (v2f){alpha, alpha}, osum);
        m_w = m_new;
    }

    if (l < 32) s_out[b * T_DIM + tw0 + l] = sv;

    // combine 4 waves -> per-tile (m, l, o[128])
    oc[wv][2 * l] = o.x;
    oc[wv][2 * l + 1] = o.y;
    if (l == 0) { mwl[wv] = m_w; lwl[wv] = l_w; }
    __syncthreads();
    if (tid < H_DIM) {
        const float mb = fmaxf(fmaxf(mwl[0], mwl[1]), fmaxf(mwl[2], mwl[3]));
        const float mu = (mb == NEG_INF) ? 0.0f : mb;
        const float b0 = __expf(mwl[0] - mu), b1 = __expf(mwl[1] - mu);
        const float b2 = __expf(mwl[2] - mu), b3 = __expf(mwl[3] - mu);
        const float ov = oc[0][tid] * b0 + oc[1][tid] * b1 + oc[2][tid] * b2 + oc[3][tid] * b3;
        const int tbase = b * NTILE + tl;
        o_part[tbase * H_DIM + tid] = ov;
        if (tid == 0) {
            ml_part[tbase * 2] = mb;
            ml_part[tbase * 2 + 1] = lwl[0] * b0 + lwl[1] * b1 + lwl[2] * b2 + lwl[3] * b3;
        }
    }
}

// k5: per-b global combine + alignment/cum epilogue
__global__ __launch_bounds__(256)
void k5_final(float* __restrict__ s_align, const float* __restrict__ cum_in,
              float* __restrict__ cum_out, const float* __restrict__ o_part,
              const float* __restrict__ ml_part, float* __restrict__ ctx) {
    const int b = blockIdx.x, tid = threadIdx.x;
    __shared__ float sm[NTILE], sl[NTILE], sb[NTILE];
    if (tid < NTILE) {
        sm[tid] = ml_part[(b * NTILE + tid) * 2];
        sl[tid] = ml_part[(b * NTILE + tid) * 2 + 1];
    }
    __syncthreads();
    float M = sm[0];
    #pragma unroll
    for (int i = 1; i < NTILE; ++i) M = fmaxf(M, sm[i]);
    const float M_use = (M == NEG_INF) ? 0.0f : M;
    if (tid < NTILE) sb[tid] = __expf(sm[tid] - M_use);
    __syncthreads();
    float L = 0.0f;
    #pragma unroll
    for (int i = 0; i < NTILE; ++i) L = fmaf(sl[i], sb[i], L);
    const float invL = 1.0f / L;
    if (tid < H_DIM) {
        float ov = 0.0f;
        #pragma unroll
        for (int i = 0; i < NTILE; ++i)
            ov = fmaf(o_part[(b * NTILE + i) * H_DIM + tid], sb[i], ov);
        ctx[b * H_DIM + tid] = ov * invL;
    }
    #pragma unroll
    for (int j = 0; j < 8; ++j) {
        const int idx = b * T_DIM + tid + j * 256;
        const float a = __expf(s_align[idx] - M_use) * invL;
        s_align[idx] = a;
        cum_out[idx] = cum_in[idx] + a;
    }
}

extern "C" void kernel_launch(void* const* d_in, const int* in_sizes, int n_in,
                              void* d_out, int out_size, void* d_ws, size_t ws_size,
                              hipStream_t stream) {
    const float* enc     = (const float*)d_in[0];
    const void*  mask    = d_in[1];
    const float* query   = (const float*)d_in[2];
    const float* cum     = (const float*)d_in[3];
    const float* conv_w  = (const float*)d_in[4];
    const float* conv_b  = (const float*)d_in[5];
    const float* Wq      = (const float*)d_in[6];
    const float* bq      = (const float*)d_in[7];
    const float* Wa      = (const float*)d_in[8];
    const float* ba      = (const float*)d_in[9];
    const float* score_w = (const float*)d_in[10];
    const float* score_b = (const float*)d_in[11];

    float* ctx_out   = (float*)d_out;                    // [B,H]
    float* cum_out   = ctx_out + B_DIM * H_DIM;          // [B,T]
    float* align_out = cum_out + B_DIM * T_DIM;          // [B,T]

    float* Gt     = (float*)d_ws;                        // [k][h] (pad 4096)
    float* qb     = Gt + 4096;                           // [B,H]
    float* o_part = qb + B_DIM * H_DIM;                  // [B,NTILE,H]
    float* ml     = o_part + B_DIM * NTILE * H_DIM;      // [B,NTILE,2]
    float* cpad   = ml + 8192;                           // [B][T+32]
    float* mb     = cpad + B_DIM * CPAD_ROW;             // [B,T]

    k_prep<<<B_DIM * T_DIM / 256, 256, 0, stream>>>(cum, mask, cpad, mb);
    k0_G<<<16, 256, 0, stream>>>(Wa, conv_w, Gt);
    k1_query<<<B_DIM, 512, 0, stream>>>(query, Wq, bq, Wa, conv_b, ba, score_b, qb);
    k2_fused<<<dim3(B_DIM, NTILE), 256, 0, stream>>>(enc, cpad, mb, Gt, qb, score_w,
                                                     align_out, o_part, ml);
    k5_final<<<B_DIM, 256, 0, stream>>>(align_out, cum, cum_out, o_part, ml, ctx_out);
}